// Round 1
// baseline (1460.842 us; speedup 1.0000x reference)
//
#include <hip/hip_runtime.h>
#include <hip/hip_bf16.h>
#include <math.h>

#define S     2048
#define HID   768
#define NQ    12
#define NKV   3
#define HD    64
#define DQKV  1152   // (NQ + 2*NKV) * HD
#define NE    16
#define FF    1536
#define EPS_R 1e-6f

// ---------------- RMSNorm: one block per row ----------------
__global__ __launch_bounds__(256) void rmsnorm_kernel(const float* __restrict__ in,
                                                      const float* __restrict__ w,
                                                      float* __restrict__ out) {
  const int t = blockIdx.x;
  const int tid = threadIdx.x;
  const float* row = in + (size_t)t * HID;
  float ss = 0.f;
  for (int i = tid; i < HID; i += 256) { float x = row[i]; ss += x * x; }
  #pragma unroll
  for (int off = 32; off >= 1; off >>= 1) ss += __shfl_xor(ss, off);
  __shared__ float ws4[4];
  if ((tid & 63) == 0) ws4[tid >> 6] = ss;
  __syncthreads();
  const float tot = ws4[0] + ws4[1] + ws4[2] + ws4[3];
  const float scale = 1.0f / sqrtf(tot * (1.0f / HID) + EPS_R);
  float* orow = out + (size_t)t * HID;
  for (int i = tid; i < HID; i += 256) orow[i] = row[i] * scale * w[i];
}

// ---------------- RoPE tables ----------------
__global__ __launch_bounds__(256) void rope_tab_kernel(float* __restrict__ cosb,
                                                       float* __restrict__ sinb) {
  const int gid = blockIdx.x * 256 + threadIdx.x;  // S*32 total
  const int pos = gid >> 5, i = gid & 31;
  const float inv = powf(10000.0f, -(float)i * (1.0f / 32.0f));
  const float f = (float)pos * inv;
  cosb[gid] = cosf(f);
  sinb[gid] = sinf(f);
}

// ---------------- RoPE apply (q and k) ----------------
__global__ __launch_bounds__(256) void rope_apply_kernel(const float* __restrict__ qkv,
                                                         const float* __restrict__ cosb,
                                                         const float* __restrict__ sinb,
                                                         float* __restrict__ q_rope,
                                                         float* __restrict__ k_rope) {
  const int gid = blockIdx.x * 256 + threadIdx.x;  // S * 15 * 32
  const int pos = gid / 480;
  const int rem = gid - pos * 480;
  const int hh = rem >> 5, i = rem & 31;
  const float c = cosb[pos * 32 + i], s = sinb[pos * 32 + i];
  const float* bp;
  float* op;
  if (hh < NQ) {
    bp = qkv + (size_t)pos * DQKV + hh * HD;
    op = q_rope + (size_t)pos * (NQ * HD) + hh * HD;
  } else {
    bp = qkv + (size_t)pos * DQKV + NQ * HD + (hh - NQ) * HD;
    op = k_rope + (size_t)pos * (NKV * HD) + (hh - NQ) * HD;
  }
  const float t0 = bp[2 * i], t1 = bp[2 * i + 1];
  op[2 * i]     = t0 * c - t1 * s;
  op[2 * i + 1] = t0 * s + t1 * c;
}

// ---------------- generic fp32 GEMM: C = A@B (+resid), 64x64 tile ----------------
__global__ __launch_bounds__(256) void gemm_rn_kernel(const float* __restrict__ A,
                                                      const float* __restrict__ B,
                                                      float* __restrict__ C,
                                                      const float* __restrict__ resid,
                                                      int M, int N, int K) {
  const int n0 = blockIdx.x * 64, m0 = blockIdx.y * 64;
  __shared__ float As[16][68], Bs[16][68];
  const int tid = threadIdx.x;
  const int ty = tid >> 4, tx = tid & 15;
  const int lm = tid >> 2, lkc = tid & 3;
  const int lk = tid >> 4, lnc = tid & 15;
  float acc[4][4] = {};
  for (int k0 = 0; k0 < K; k0 += 16) {
    const float4 a4 = *(const float4*)(A + (size_t)(m0 + lm) * K + k0 + lkc * 4);
    As[lkc * 4 + 0][lm] = a4.x; As[lkc * 4 + 1][lm] = a4.y;
    As[lkc * 4 + 2][lm] = a4.z; As[lkc * 4 + 3][lm] = a4.w;
    *(float4*)&Bs[lk][lnc * 4] = *(const float4*)(B + (size_t)(k0 + lk) * N + n0 + lnc * 4);
    __syncthreads();
    #pragma unroll
    for (int k = 0; k < 16; ++k) {
      const float4 a = *(const float4*)&As[k][ty * 4];
      const float4 b = *(const float4*)&Bs[k][tx * 4];
      const float av[4] = {a.x, a.y, a.z, a.w};
      const float bv[4] = {b.x, b.y, b.z, b.w};
      #pragma unroll
      for (int i = 0; i < 4; ++i)
        #pragma unroll
        for (int j = 0; j < 4; ++j) acc[i][j] += av[i] * bv[j];
    }
    __syncthreads();
  }
  #pragma unroll
  for (int i = 0; i < 4; ++i) {
    const int m = m0 + ty * 4 + i;
    #pragma unroll
    for (int j = 0; j < 4; ++j) {
      const int n = n0 + tx * 4 + j;
      float v = acc[i][j];
      if (resid) v += resid[(size_t)m * N + n];
      C[(size_t)m * N + n] = v;
    }
  }
}

// ---------------- flash attention fp32, GQA, causal ----------------
// grid: (S/64 qtiles, NQ heads), block 256. Thread (r=tid>>2, dc=tid&3) owns
// q-row r, score cols c = dc+4j, out dims d = dc*16+j.
__global__ __launch_bounds__(256) void attn_kernel(const float* __restrict__ q,
                                                   const float* __restrict__ kr,
                                                   const float* __restrict__ qkv,
                                                   float* __restrict__ ctx) {
  const int qt = blockIdx.x, qh = blockIdx.y, kvh = qh >> 2;
  __shared__ float Qs[64][68], Ks[64][68], Vs[64][68];
  const int tid = threadIdx.x;
  const int r = tid >> 2, dc = tid & 3;
  for (int idx = tid; idx < 4096; idx += 256) {
    const int rr = idx >> 6, d = idx & 63;
    Qs[rr][d] = q[(size_t)(qt * 64 + rr) * (NQ * HD) + qh * HD + d];
  }
  float acc[16];
  #pragma unroll
  for (int j = 0; j < 16; ++j) acc[j] = 0.f;
  float mrow = -INFINITY, lrow = 0.f;

  for (int kt = 0; kt <= qt; ++kt) {
    __syncthreads();  // previous PV done before overwriting Ks/Vs
    for (int idx = tid; idx < 4096; idx += 256) {
      const int rr = idx >> 6, d = idx & 63;
      Ks[rr][d] = kr[(size_t)(kt * 64 + rr) * (NKV * HD) + kvh * HD + d];
      Vs[rr][d] = qkv[(size_t)(kt * 64 + rr) * DQKV + (NQ + NKV) * HD + kvh * HD + d];
    }
    __syncthreads();

    float sj[16];
    #pragma unroll
    for (int j = 0; j < 16; ++j) sj[j] = 0.f;
    #pragma unroll 4
    for (int d4 = 0; d4 < 16; ++d4) {
      const float4 q4 = *(const float4*)&Qs[r][d4 * 4];
      #pragma unroll
      for (int j = 0; j < 16; ++j) {
        const float4 k4 = *(const float4*)&Ks[dc + 4 * j][d4 * 4];
        sj[j] += q4.x * k4.x + q4.y * k4.y + q4.z * k4.z + q4.w * k4.w;
      }
    }
    float pm = -INFINITY;
    #pragma unroll
    for (int j = 0; j < 16; ++j) {
      float sv = sj[j] * 0.125f;
      if (kt == qt && (dc + 4 * j) > r) sv = -INFINITY;
      sj[j] = sv;
      pm = fmaxf(pm, sv);
    }
    pm = fmaxf(pm, __shfl_xor(pm, 1));
    pm = fmaxf(pm, __shfl_xor(pm, 2));
    const float mn = fmaxf(mrow, pm);
    const float corr = expf(mrow - mn);  // first tile: expf(-inf)=0
    float psum = 0.f;
    #pragma unroll
    for (int j = 0; j < 16; ++j) { const float pj = expf(sj[j] - mn); sj[j] = pj; psum += pj; }
    psum += __shfl_xor(psum, 1);
    psum += __shfl_xor(psum, 2);
    lrow = lrow * corr + psum;
    #pragma unroll
    for (int j = 0; j < 16; ++j) acc[j] *= corr;
    mrow = mn;
    __syncthreads();  // all reads of Ks finished
    #pragma unroll
    for (int j = 0; j < 16; ++j) Ks[r][dc + 4 * j] = sj[j];  // P tile into Ks buffer
    __syncthreads();
    for (int c = 0; c < 64; ++c) {
      const float pv = Ks[r][c];
      const float4 v0 = *(const float4*)&Vs[c][dc * 16 + 0];
      const float4 v1 = *(const float4*)&Vs[c][dc * 16 + 4];
      const float4 v2 = *(const float4*)&Vs[c][dc * 16 + 8];
      const float4 v3 = *(const float4*)&Vs[c][dc * 16 + 12];
      acc[0]  += pv * v0.x; acc[1]  += pv * v0.y; acc[2]  += pv * v0.z; acc[3]  += pv * v0.w;
      acc[4]  += pv * v1.x; acc[5]  += pv * v1.y; acc[6]  += pv * v1.z; acc[7]  += pv * v1.w;
      acc[8]  += pv * v2.x; acc[9]  += pv * v2.y; acc[10] += pv * v2.z; acc[11] += pv * v2.w;
      acc[12] += pv * v3.x; acc[13] += pv * v3.y; acc[14] += pv * v3.z; acc[15] += pv * v3.w;
    }
  }
  const float inv_l = 1.0f / lrow;
  #pragma unroll
  for (int j = 0; j < 16; ++j)
    ctx[(size_t)(qt * 64 + r) * (NQ * HD) + qh * HD + dc * 16 + j] = acc[j] * inv_l;
}

// ---------------- router: logits -> softmax -> top2 -> counts ----------------
__global__ __launch_bounds__(256) void router_kernel(const float* __restrict__ xin,
                                                     const float* __restrict__ wr,
                                                     int* __restrict__ eidx,
                                                     float* __restrict__ wnorm,
                                                     int* __restrict__ counts) {
  const int t = blockIdx.x, tid = threadIdx.x;
  __shared__ float xs[HID];
  __shared__ float part[16][17];
  __shared__ float logits[16];
  for (int i = tid; i < HID; i += 256) xs[i] = xin[(size_t)t * HID + i];
  __syncthreads();
  const int e = tid & 15, chunk = tid >> 4;
  float s = 0.f;
  for (int r2 = chunk * 48; r2 < chunk * 48 + 48; ++r2) s += xs[r2] * wr[r2 * NE + e];
  part[chunk][e] = s;
  __syncthreads();
  if (tid < 16) {
    float l = 0.f;
    for (int c2 = 0; c2 < 16; ++c2) l += part[c2][tid];
    logits[tid] = l;
  }
  __syncthreads();
  if (tid == 0) {
    float m = logits[0];
    for (int i = 1; i < NE; ++i) m = fmaxf(m, logits[i]);
    float pex[NE];
    for (int i = 0; i < NE; ++i) pex[i] = expf(logits[i] - m);
    int i0 = 0; float v0 = pex[0];
    for (int i = 1; i < NE; ++i) if (pex[i] > v0) { v0 = pex[i]; i0 = i; }
    int i1 = -1; float v1 = -1.f;
    for (int i = 0; i < NE; ++i) { if (i == i0) continue; if (pex[i] > v1) { v1 = pex[i]; i1 = i; } }
    const float wsum = v0 + v1;
    eidx[t * 2] = i0; eidx[t * 2 + 1] = i1;
    wnorm[t * 2] = v0 / wsum; wnorm[t * 2 + 1] = v1 / wsum;
    atomicAdd(&counts[i0], 1);
    atomicAdd(&counts[i1], 1);
  }
}

__global__ void zero_counts_kernel(int* __restrict__ counts) {
  if (threadIdx.x < NE) counts[threadIdx.x] = 0;
}

__global__ void offsets_kernel(const int* __restrict__ counts, int* __restrict__ offs,
                               int* __restrict__ cursors) {
  if (threadIdx.x == 0) {
    int acc = 0;
    for (int e = 0; e < NE; ++e) { offs[e] = acc; cursors[e] = acc; acc += counts[e]; }
    offs[NE] = acc;
  }
}

__global__ __launch_bounds__(256) void scatter_kernel(const int* __restrict__ eidx,
                                                      const float* __restrict__ wnorm,
                                                      int* __restrict__ cursors,
                                                      int* __restrict__ pair_token,
                                                      float* __restrict__ pair_w,
                                                      int* __restrict__ pos_of) {
  const int t = blockIdx.x * 256 + threadIdx.x;  // token
  for (int slot = 0; slot < 2; ++slot) {
    const int e = eidx[t * 2 + slot];
    const int pos = atomicAdd(&cursors[e], 1);
    pair_token[pos] = t;
    pair_w[pos] = wnorm[t * 2 + slot];
    pos_of[t * 2 + slot] = pos;
  }
}

// ---------------- MoE grouped GEMM 1: h_ff = silu(x@Wg) * (x@Wu) ----------------
__global__ __launch_bounds__(256) void moe_gemm1_kernel(const float* __restrict__ X,
                                                        const float* __restrict__ Wgu,
                                                        const int* __restrict__ ptok,
                                                        const int* __restrict__ offs,
                                                        float* __restrict__ hff) {
  const int e = blockIdx.z;
  const int off = offs[e], cnt = offs[e + 1] - off;
  const int m0 = blockIdx.y * 64;
  if (m0 >= cnt) return;
  const int n0 = blockIdx.x * 64;
  const float* B = Wgu + (size_t)e * HID * (2 * FF);
  __shared__ float As[16][68], Bg[16][68], Bu[16][68];
  const int tid = threadIdx.x, ty = tid >> 4, tx = tid & 15;
  const int lm = tid >> 2, lkc = tid & 3;
  const int lk = tid >> 4, lnc = tid & 15;
  float accg[4][4] = {}, accu[4][4] = {};
  const float* arow = nullptr;
  if (m0 + lm < cnt) arow = X + (size_t)ptok[off + m0 + lm] * HID;
  for (int k0 = 0; k0 < HID; k0 += 16) {
    float4 a4 = make_float4(0.f, 0.f, 0.f, 0.f);
    if (arow) a4 = *(const float4*)(arow + k0 + lkc * 4);
    As[lkc * 4 + 0][lm] = a4.x; As[lkc * 4 + 1][lm] = a4.y;
    As[lkc * 4 + 2][lm] = a4.z; As[lkc * 4 + 3][lm] = a4.w;
    const float* brow = B + (size_t)(k0 + lk) * (2 * FF) + n0 + lnc * 4;
    *(float4*)&Bg[lk][lnc * 4] = *(const float4*)(brow);
    *(float4*)&Bu[lk][lnc * 4] = *(const float4*)(brow + FF);
    __syncthreads();
    #pragma unroll
    for (int k = 0; k < 16; ++k) {
      const float4 a = *(const float4*)&As[k][ty * 4];
      const float4 g = *(const float4*)&Bg[k][tx * 4];
      const float4 u = *(const float4*)&Bu[k][tx * 4];
      const float av[4] = {a.x, a.y, a.z, a.w};
      const float gv[4] = {g.x, g.y, g.z, g.w};
      const float uv[4] = {u.x, u.y, u.z, u.w};
      #pragma unroll
      for (int i = 0; i < 4; ++i)
        #pragma unroll
        for (int j = 0; j < 4; ++j) {
          accg[i][j] += av[i] * gv[j];
          accu[i][j] += av[i] * uv[j];
        }
    }
    __syncthreads();
  }
  #pragma unroll
  for (int i = 0; i < 4; ++i) {
    const int m = m0 + ty * 4 + i;
    if (m < cnt) {
      #pragma unroll
      for (int j = 0; j < 4; ++j) {
        const float g = accg[i][j], u = accu[i][j];
        const float hv = g / (1.0f + expf(-g)) * u;  // silu(g)*u
        hff[(size_t)(off + m) * FF + n0 + tx * 4 + j] = hv;
      }
    }
  }
}

// ---------------- MoE grouped GEMM 2: pair_out = (h_ff @ Wd) * pair_w ----------------
__global__ __launch_bounds__(256) void moe_gemm2_kernel(const float* __restrict__ hff,
                                                        const float* __restrict__ Wd,
                                                        const float* __restrict__ pair_w,
                                                        const int* __restrict__ offs,
                                                        float* __restrict__ pout) {
  const int e = blockIdx.z;
  const int off = offs[e], cnt = offs[e + 1] - off;
  const int m0 = blockIdx.y * 64;
  if (m0 >= cnt) return;
  const int n0 = blockIdx.x * 64;
  const float* B = Wd + (size_t)e * FF * HID;
  __shared__ float As[16][68], Bs[16][68];
  const int tid = threadIdx.x, ty = tid >> 4, tx = tid & 15;
  const int lm = tid >> 2, lkc = tid & 3;
  const int lk = tid >> 4, lnc = tid & 15;
  float acc[4][4] = {};
  const bool arow_ok = (m0 + lm < cnt);
  const float* arow = hff + (size_t)(off + m0 + lm) * FF;
  for (int k0 = 0; k0 < FF; k0 += 16) {
    float4 a4 = make_float4(0.f, 0.f, 0.f, 0.f);
    if (arow_ok) a4 = *(const float4*)(arow + k0 + lkc * 4);
    As[lkc * 4 + 0][lm] = a4.x; As[lkc * 4 + 1][lm] = a4.y;
    As[lkc * 4 + 2][lm] = a4.z; As[lkc * 4 + 3][lm] = a4.w;
    *(float4*)&Bs[lk][lnc * 4] = *(const float4*)(B + (size_t)(k0 + lk) * HID + n0 + lnc * 4);
    __syncthreads();
    #pragma unroll
    for (int k = 0; k < 16; ++k) {
      const float4 a = *(const float4*)&As[k][ty * 4];
      const float4 b = *(const float4*)&Bs[k][tx * 4];
      const float av[4] = {a.x, a.y, a.z, a.w};
      const float bv[4] = {b.x, b.y, b.z, b.w};
      #pragma unroll
      for (int i = 0; i < 4; ++i)
        #pragma unroll
        for (int j = 0; j < 4; ++j) acc[i][j] += av[i] * bv[j];
    }
    __syncthreads();
  }
  #pragma unroll
  for (int i = 0; i < 4; ++i) {
    const int m = m0 + ty * 4 + i;
    if (m < cnt) {
      const float pw = pair_w[off + m];
      #pragma unroll
      for (int j = 0; j < 4; ++j)
        pout[(size_t)(off + m) * HID + n0 + tx * 4 + j] = acc[i][j] * pw;
    }
  }
}

// ---------------- final: out = h + pair_out[pos0] + pair_out[pos1] ----------------
__global__ __launch_bounds__(256) void final_kernel(const float* __restrict__ h,
                                                    const float* __restrict__ pout,
                                                    const int* __restrict__ pos_of,
                                                    float* __restrict__ out) {
  const int gid = blockIdx.x * 256 + threadIdx.x;  // S*HID
  const int t = gid / HID, c = gid - t * HID;
  const int p0 = pos_of[2 * t], p1 = pos_of[2 * t + 1];
  out[gid] = h[gid] + pout[(size_t)p0 * HID + c] + pout[(size_t)p1 * HID + c];
}

// ---------------- launch ----------------
extern "C" void kernel_launch(void* const* d_in, const int* in_sizes, int n_in,
                              void* d_out, int out_size, void* d_ws, size_t ws_size,
                              hipStream_t stream) {
  const float* x         = (const float*)d_in[0];
  const float* norm1_w   = (const float*)d_in[1];
  const float* w_qkv     = (const float*)d_in[2];
  const float* w_out     = (const float*)d_in[3];
  const float* norm2_w   = (const float*)d_in[4];
  const float* w_router  = (const float*)d_in[5];
  const float* w_gate_up = (const float*)d_in[6];
  const float* w_down    = (const float*)d_in[7];
  float* out = (float*)d_out;

  char* p = (char*)d_ws;
  auto alloc = [&](size_t bytes) -> void* {
    void* r = (void*)p;
    p += (bytes + 255) & ~(size_t)255;
    return r;
  };
  float* xn       = (float*)alloc((size_t)S * HID * 4);
  float* qkv      = (float*)alloc((size_t)S * DQKV * 4);
  float* cosb     = (float*)alloc((size_t)S * 32 * 4);
  float* sinb     = (float*)alloc((size_t)S * 32 * 4);
  float* q_rope   = (float*)alloc((size_t)S * NQ * HD * 4);
  float* k_rope   = (float*)alloc((size_t)S * NKV * HD * 4);
  float* ctxb     = (float*)alloc((size_t)S * HID * 4);
  float* hbuf     = (float*)alloc((size_t)S * HID * 4);
  float* moe_in   = (float*)alloc((size_t)S * HID * 4);
  float* h_ff     = (float*)alloc((size_t)2 * S * FF * 4);
  float* pout     = (float*)alloc((size_t)2 * S * HID * 4);
  float* wnorm    = (float*)alloc((size_t)S * 2 * 4);
  float* pair_w   = (float*)alloc((size_t)S * 2 * 4);
  int* eidx       = (int*)alloc((size_t)S * 2 * 4);
  int* counts     = (int*)alloc(64 * 4);
  int* offs       = (int*)alloc(64 * 4);
  int* cursors    = (int*)alloc(64 * 4);
  int* pair_token = (int*)alloc((size_t)S * 2 * 4);
  int* pos_of     = (int*)alloc((size_t)S * 2 * 4);

  rmsnorm_kernel<<<S, 256, 0, stream>>>(x, norm1_w, xn);
  rope_tab_kernel<<<(S * 32) / 256, 256, 0, stream>>>(cosb, sinb);
  gemm_rn_kernel<<<dim3(DQKV / 64, S / 64), 256, 0, stream>>>(xn, w_qkv, qkv, nullptr, S, DQKV, HID);
  rope_apply_kernel<<<(S * 15 * 32) / 256, 256, 0, stream>>>(qkv, cosb, sinb, q_rope, k_rope);
  attn_kernel<<<dim3(S / 64, NQ), 256, 0, stream>>>(q_rope, k_rope, qkv, ctxb);
  gemm_rn_kernel<<<dim3(HID / 64, S / 64), 256, 0, stream>>>(ctxb, w_out, hbuf, x, S, HID, HID);
  rmsnorm_kernel<<<S, 256, 0, stream>>>(hbuf, norm2_w, moe_in);
  zero_counts_kernel<<<1, 64, 0, stream>>>(counts);
  router_kernel<<<S, 256, 0, stream>>>(moe_in, w_router, eidx, wnorm, counts);
  offsets_kernel<<<1, 1, 0, stream>>>(counts, offs, cursors);
  scatter_kernel<<<S / 256, 256, 0, stream>>>(eidx, wnorm, cursors, pair_token, pair_w, pos_of);
  moe_gemm1_kernel<<<dim3(FF / 64, 32, NE), 256, 0, stream>>>(moe_in, w_gate_up, pair_token, offs, h_ff);
  moe_gemm2_kernel<<<dim3(HID / 64, 32, NE), 256, 0, stream>>>(h_ff, w_down, pair_w, offs, pout);
  final_kernel<<<(S * HID) / 256, 256, 0, stream>>>(hbuf, pout, pos_of, out);
}

// Round 2
// 976.704 us; speedup vs baseline: 1.4957x; 1.4957x over previous
//
#include <hip/hip_runtime.h>
#include <hip/hip_bf16.h>
#include <math.h>

#define S     2048
#define HID   768
#define NQ    12
#define NKV   3
#define HD    64
#define DQKV  1152   // (NQ + 2*NKV) * HD
#define NE    16
#define FF    1536
#define EPS_R 1e-6f

typedef __attribute__((ext_vector_type(8))) short bf16x8;
typedef __attribute__((ext_vector_type(8))) unsigned short u16x8;
typedef __attribute__((ext_vector_type(4))) float f32x4;

__device__ __forceinline__ unsigned short f2bf(float f) {
  union { float f; unsigned u; } v; v.f = f;
  unsigned r = v.u + 0x7fffu + ((v.u >> 16) & 1u);
  return (unsigned short)(r >> 16);
}

// ---------------- RMSNorm: one block per row ----------------
__global__ __launch_bounds__(256) void rmsnorm_kernel(const float* __restrict__ in,
                                                      const float* __restrict__ w,
                                                      float* __restrict__ out) {
  const int t = blockIdx.x;
  const int tid = threadIdx.x;
  const float* row = in + (size_t)t * HID;
  float ss = 0.f;
  for (int i = tid; i < HID; i += 256) { float x = row[i]; ss += x * x; }
  #pragma unroll
  for (int off = 32; off >= 1; off >>= 1) ss += __shfl_xor(ss, off);
  __shared__ float ws4[4];
  if ((tid & 63) == 0) ws4[tid >> 6] = ss;
  __syncthreads();
  const float tot = ws4[0] + ws4[1] + ws4[2] + ws4[3];
  const float scale = 1.0f / sqrtf(tot * (1.0f / HID) + EPS_R);
  float* orow = out + (size_t)t * HID;
  for (int i = tid; i < HID; i += 256) orow[i] = row[i] * scale * w[i];
}

// ---------------- cast fp32 -> bf16 ----------------
__global__ __launch_bounds__(256) void cast_bf_kernel(const float* __restrict__ in,
                                                      unsigned short* __restrict__ out) {
  const int gid = blockIdx.x * 256 + threadIdx.x;  // S*HID/4 threads
  const float4 v = *(const float4*)(in + (size_t)gid * 4);
  unsigned short o[4] = {f2bf(v.x), f2bf(v.y), f2bf(v.z), f2bf(v.w)};
  *(ulong1*)(out + (size_t)gid * 4) = *(ulong1*)o;
}

// ---------------- RoPE tables ----------------
__global__ __launch_bounds__(256) void rope_tab_kernel(float* __restrict__ cosb,
                                                       float* __restrict__ sinb) {
  const int gid = blockIdx.x * 256 + threadIdx.x;  // S*32 total
  const int pos = gid >> 5, i = gid & 31;
  const float inv = powf(10000.0f, -(float)i * (1.0f / 32.0f));
  const float f = (float)pos * inv;
  cosb[gid] = cosf(f);
  sinb[gid] = sinf(f);
}

// ---------------- RoPE apply (q and k) ----------------
__global__ __launch_bounds__(256) void rope_apply_kernel(const float* __restrict__ qkv,
                                                         const float* __restrict__ cosb,
                                                         const float* __restrict__ sinb,
                                                         float* __restrict__ q_rope,
                                                         float* __restrict__ k_rope) {
  const int gid = blockIdx.x * 256 + threadIdx.x;  // S * 15 * 32
  const int pos = gid / 480;
  const int rem = gid - pos * 480;
  const int hh = rem >> 5, i = rem & 31;
  const float c = cosb[pos * 32 + i], s = sinb[pos * 32 + i];
  const float* bp;
  float* op;
  if (hh < NQ) {
    bp = qkv + (size_t)pos * DQKV + hh * HD;
    op = q_rope + (size_t)pos * (NQ * HD) + hh * HD;
  } else {
    bp = qkv + (size_t)pos * DQKV + NQ * HD + (hh - NQ) * HD;
    op = k_rope + (size_t)pos * (NKV * HD) + (hh - NQ) * HD;
  }
  const float t0 = bp[2 * i], t1 = bp[2 * i + 1];
  op[2 * i]     = t0 * c - t1 * s;
  op[2 * i + 1] = t0 * s + t1 * c;
}

// ---------------- generic fp32 GEMM: C = A@B (+resid), 64x64 tile ----------------
__global__ __launch_bounds__(256) void gemm_rn_kernel(const float* __restrict__ A,
                                                      const float* __restrict__ B,
                                                      float* __restrict__ C,
                                                      const float* __restrict__ resid,
                                                      int M, int N, int K) {
  const int n0 = blockIdx.x * 64, m0 = blockIdx.y * 64;
  __shared__ float As[16][68], Bs[16][68];
  const int tid = threadIdx.x;
  const int ty = tid >> 4, tx = tid & 15;
  const int lm = tid >> 2, lkc = tid & 3;
  const int lk = tid >> 4, lnc = tid & 15;
  float acc[4][4] = {};
  for (int k0 = 0; k0 < K; k0 += 16) {
    const float4 a4 = *(const float4*)(A + (size_t)(m0 + lm) * K + k0 + lkc * 4);
    As[lkc * 4 + 0][lm] = a4.x; As[lkc * 4 + 1][lm] = a4.y;
    As[lkc * 4 + 2][lm] = a4.z; As[lkc * 4 + 3][lm] = a4.w;
    *(float4*)&Bs[lk][lnc * 4] = *(const float4*)(B + (size_t)(k0 + lk) * N + n0 + lnc * 4);
    __syncthreads();
    #pragma unroll
    for (int k = 0; k < 16; ++k) {
      const float4 a = *(const float4*)&As[k][ty * 4];
      const float4 b = *(const float4*)&Bs[k][tx * 4];
      const float av[4] = {a.x, a.y, a.z, a.w};
      const float bv[4] = {b.x, b.y, b.z, b.w};
      #pragma unroll
      for (int i = 0; i < 4; ++i)
        #pragma unroll
        for (int j = 0; j < 4; ++j) acc[i][j] += av[i] * bv[j];
    }
    __syncthreads();
  }
  #pragma unroll
  for (int i = 0; i < 4; ++i) {
    const int m = m0 + ty * 4 + i;
    #pragma unroll
    for (int j = 0; j < 4; ++j) {
      const int n = n0 + tx * 4 + j;
      float v = acc[i][j];
      if (resid) v += resid[(size_t)m * N + n];
      C[(size_t)m * N + n] = v;
    }
  }
}

// ---------------- flash attention fp32 v2: 4x4 register patches ----------------
// grid: (S/64 qtiles, NQ heads), block 256. Thread (ty=tid>>4, tx=tid&15):
//   score patch rows ty*4+i, score cols tx+16*j; out dims tx*4+j.
__global__ __launch_bounds__(256) void attn_v2_kernel(const float* __restrict__ q,
                                                      const float* __restrict__ kr,
                                                      const float* __restrict__ qkv,
                                                      float* __restrict__ ctx) {
  const int qt = blockIdx.x, qh = blockIdx.y, kvh = qh >> 2;
  __shared__ float Qs[64][68], Ks[64][68], Vs[64][68];
  const int tid = threadIdx.x;
  const int ty = tid >> 4, tx = tid & 15;
  for (int idx = tid; idx < 4096; idx += 256) {
    const int rr = idx >> 6, d = idx & 63;
    Qs[rr][d] = q[(size_t)(qt * 64 + rr) * (NQ * HD) + qh * HD + d];
  }
  float acc[4][4] = {};
  float mrow[4] = {-INFINITY, -INFINITY, -INFINITY, -INFINITY};
  float lrow[4] = {0.f, 0.f, 0.f, 0.f};

  for (int kt = 0; kt <= qt; ++kt) {
    __syncthreads();  // previous PV reads done before overwriting Ks/Vs
    for (int idx = tid; idx < 4096; idx += 256) {
      const int rr = idx >> 6, d = idx & 63;
      Ks[rr][d] = kr[(size_t)(kt * 64 + rr) * (NKV * HD) + kvh * HD + d];
      Vs[rr][d] = qkv[(size_t)(kt * 64 + rr) * DQKV + (NQ + NKV) * HD + kvh * HD + d];
    }
    __syncthreads();

    float s[4][4] = {};
    #pragma unroll 4
    for (int d4 = 0; d4 < 16; ++d4) {
      float4 qv[4];
      #pragma unroll
      for (int i = 0; i < 4; ++i) qv[i] = *(const float4*)&Qs[ty * 4 + i][d4 * 4];
      #pragma unroll
      for (int j = 0; j < 4; ++j) {
        const float4 kv = *(const float4*)&Ks[tx + 16 * j][d4 * 4];
        #pragma unroll
        for (int i = 0; i < 4; ++i)
          s[i][j] += qv[i].x * kv.x + qv[i].y * kv.y + qv[i].z * kv.z + qv[i].w * kv.w;
      }
    }
    // scale + causal mask + row max
    float pm[4] = {-INFINITY, -INFINITY, -INFINITY, -INFINITY};
    #pragma unroll
    for (int i = 0; i < 4; ++i)
      #pragma unroll
      for (int j = 0; j < 4; ++j) {
        float sv = s[i][j] * 0.125f;
        if (kt == qt && (tx + 16 * j) > (ty * 4 + i)) sv = -INFINITY;
        s[i][j] = sv;
        pm[i] = fmaxf(pm[i], sv);
      }
    #pragma unroll
    for (int off = 8; off >= 1; off >>= 1)
      #pragma unroll
      for (int i = 0; i < 4; ++i) pm[i] = fmaxf(pm[i], __shfl_xor(pm[i], off));
    float corr[4], ps[4];
    #pragma unroll
    for (int i = 0; i < 4; ++i) {
      const float mn = fmaxf(mrow[i], pm[i]);
      corr[i] = expf(mrow[i] - mn);
      mrow[i] = mn;
      ps[i] = 0.f;
      #pragma unroll
      for (int j = 0; j < 4; ++j) {
        const float pj = expf(s[i][j] - mn);
        s[i][j] = pj;
        ps[i] += pj;
      }
    }
    #pragma unroll
    for (int off = 8; off >= 1; off >>= 1)
      #pragma unroll
      for (int i = 0; i < 4; ++i) ps[i] += __shfl_xor(ps[i], off);
    #pragma unroll
    for (int i = 0; i < 4; ++i) {
      lrow[i] = lrow[i] * corr[i] + ps[i];
      #pragma unroll
      for (int j = 0; j < 4; ++j) acc[i][j] *= corr[i];
    }
    __syncthreads();  // all Ks reads finished
    #pragma unroll
    for (int i = 0; i < 4; ++i)
      #pragma unroll
      for (int j = 0; j < 4; ++j) Ks[ty * 4 + i][tx + 16 * j] = s[i][j];  // P into Ks buffer
    __syncthreads();
    #pragma unroll 4
    for (int c = 0; c < 64; ++c) {
      float pv[4];
      #pragma unroll
      for (int i = 0; i < 4; ++i) pv[i] = Ks[ty * 4 + i][c];
      const float4 vv = *(const float4*)&Vs[c][tx * 4];
      #pragma unroll
      for (int i = 0; i < 4; ++i) {
        acc[i][0] += pv[i] * vv.x; acc[i][1] += pv[i] * vv.y;
        acc[i][2] += pv[i] * vv.z; acc[i][3] += pv[i] * vv.w;
      }
    }
  }
  #pragma unroll
  for (int i = 0; i < 4; ++i) {
    const float inv_l = 1.0f / lrow[i];
    #pragma unroll
    for (int j = 0; j < 4; ++j)
      ctx[(size_t)(qt * 64 + ty * 4 + i) * (NQ * HD) + qh * HD + tx * 4 + j] = acc[i][j] * inv_l;
  }
}

// ---------------- router: logits -> softmax -> top2 -> counts ----------------
__global__ __launch_bounds__(256) void router_kernel(const float* __restrict__ xin,
                                                     const float* __restrict__ wr,
                                                     int* __restrict__ eidx,
                                                     float* __restrict__ wnorm,
                                                     int* __restrict__ counts) {
  const int t = blockIdx.x, tid = threadIdx.x;
  __shared__ float xs[HID];
  __shared__ float part[16][17];
  __shared__ float logits[16];
  for (int i = tid; i < HID; i += 256) xs[i] = xin[(size_t)t * HID + i];
  __syncthreads();
  const int e = tid & 15, chunk = tid >> 4;
  float s = 0.f;
  for (int r2 = chunk * 48; r2 < chunk * 48 + 48; ++r2) s += xs[r2] * wr[r2 * NE + e];
  part[chunk][e] = s;
  __syncthreads();
  if (tid < 16) {
    float l = 0.f;
    for (int c2 = 0; c2 < 16; ++c2) l += part[c2][tid];
    logits[tid] = l;
  }
  __syncthreads();
  if (tid == 0) {
    float m = logits[0];
    for (int i = 1; i < NE; ++i) m = fmaxf(m, logits[i]);
    float pex[NE];
    for (int i = 0; i < NE; ++i) pex[i] = expf(logits[i] - m);
    int i0 = 0; float v0 = pex[0];
    for (int i = 1; i < NE; ++i) if (pex[i] > v0) { v0 = pex[i]; i0 = i; }
    int i1 = -1; float v1 = -1.f;
    for (int i = 0; i < NE; ++i) { if (i == i0) continue; if (pex[i] > v1) { v1 = pex[i]; i1 = i; } }
    const float wsum = v0 + v1;
    eidx[t * 2] = i0; eidx[t * 2 + 1] = i1;
    wnorm[t * 2] = v0 / wsum; wnorm[t * 2 + 1] = v1 / wsum;
    atomicAdd(&counts[i0], 1);
    atomicAdd(&counts[i1], 1);
  }
}

__global__ void zero_counts_kernel(int* __restrict__ counts) {
  if (threadIdx.x < NE) counts[threadIdx.x] = 0;
}

__global__ void offsets_kernel(const int* __restrict__ counts, int* __restrict__ offs,
                               int* __restrict__ cursors) {
  if (threadIdx.x == 0) {
    int acc = 0;
    for (int e = 0; e < NE; ++e) { offs[e] = acc; cursors[e] = acc; acc += counts[e]; }
    offs[NE] = acc;
  }
}

__global__ __launch_bounds__(256) void scatter_kernel(const int* __restrict__ eidx,
                                                      const float* __restrict__ wnorm,
                                                      int* __restrict__ cursors,
                                                      int* __restrict__ pair_token,
                                                      float* __restrict__ pair_w,
                                                      int* __restrict__ pos_of) {
  const int t = blockIdx.x * 256 + threadIdx.x;  // token
  for (int slot = 0; slot < 2; ++slot) {
    const int e = eidx[t * 2 + slot];
    const int pos = atomicAdd(&cursors[e], 1);
    pair_token[pos] = t;
    pair_w[pos] = wnorm[t * 2 + slot];
    pos_of[t * 2 + slot] = pos;
  }
}

// ---------------- MoE MFMA grouped GEMM 1: h_ff = silu(x@Wg)*(x@Wu), bf16 ----------------
// BM=128, BN=64 (gate + up in parallel). 4 waves, wave w owns rows 32w..32w+31.
__global__ __launch_bounds__(256) void moe_gemm1_mfma(const unsigned short* __restrict__ Xbf,
                                                      const float* __restrict__ Wgu,
                                                      const int* __restrict__ ptok,
                                                      const int* __restrict__ offs,
                                                      unsigned short* __restrict__ hff) {
  const int e = blockIdx.z;
  const int off = offs[e], cnt = offs[e + 1] - off;
  const int m0 = blockIdx.y * 128;
  if (m0 >= cnt) return;
  const int n0 = blockIdx.x * 64;
  const float* Bsrc = Wgu + (size_t)e * HID * (2 * FF);
  __shared__ unsigned short As[128][40];
  __shared__ unsigned short Bg[64][40];
  __shared__ unsigned short Bu[64][40];
  const int tid = threadIdx.x;
  const int lane = tid & 63, w = tid >> 6;
  const int l15 = lane & 15, qq = lane >> 4;
  const int ar = tid >> 1, ah = tid & 1;       // A staging: row, k-half
  const int bk = tid >> 3, bc8 = tid & 7;      // B staging: k, col-group
  const int bshift = 8 * (bc8 & 1);
  int tok = 0;
  const bool aok = (m0 + ar < cnt);
  if (aok) tok = ptok[off + m0 + ar];
  const unsigned short* xrow = Xbf + (size_t)tok * HID;
  const int aoff = qq * 8 + 8 * (l15 & 1);
  const int boff = qq * 8 + 8 * ((l15 >> 3) & 1);
  f32x4 accg[2][4], accu[2][4];
  #pragma unroll
  for (int r = 0; r < 2; ++r)
    #pragma unroll
    for (int n = 0; n < 4; ++n) {
      accg[r][n] = (f32x4){0.f, 0.f, 0.f, 0.f};
      accu[r][n] = (f32x4){0.f, 0.f, 0.f, 0.f};
    }
  for (int k0 = 0; k0 < HID; k0 += 32) {
    u16x8 a0 = {0, 0, 0, 0, 0, 0, 0, 0}, a1 = {0, 0, 0, 0, 0, 0, 0, 0};
    if (aok) {
      a0 = *(const u16x8*)(xrow + k0 + ah * 16);
      a1 = *(const u16x8*)(xrow + k0 + ah * 16 + 8);
    }
    const int aw = ah * 16 + 8 * (ar & 1);
    *(u16x8*)&As[ar][aw] = a0;
    *(u16x8*)&As[ar][aw + 8] = a1;
    const float* brow = Bsrc + (size_t)(k0 + bk) * (2 * FF) + n0 + bc8 * 8;
    const float4 g0 = *(const float4*)(brow);
    const float4 g1 = *(const float4*)(brow + 4);
    const float4 u0 = *(const float4*)(brow + FF);
    const float4 u1 = *(const float4*)(brow + FF + 4);
    const float gv[8] = {g0.x, g0.y, g0.z, g0.w, g1.x, g1.y, g1.z, g1.w};
    const float uv[8] = {u0.x, u0.y, u0.z, u0.w, u1.x, u1.y, u1.z, u1.w};
    #pragma unroll
    for (int ii = 0; ii < 8; ++ii) {
      Bg[bc8 * 8 + ii][bk + bshift] = f2bf(gv[ii]);
      Bu[bc8 * 8 + ii][bk + bshift] = f2bf(uv[ii]);
    }
    __syncthreads();
    const bf16x8 fa0 = *(const bf16x8*)&As[32 * w + l15][aoff];
    const bf16x8 fa1 = *(const bf16x8*)&As[32 * w + 16 + l15][aoff];
    #pragma unroll
    for (int n = 0; n < 4; ++n) {
      const bf16x8 fg = *(const bf16x8*)&Bg[n * 16 + l15][boff];
      const bf16x8 fu = *(const bf16x8*)&Bu[n * 16 + l15][boff];
      accg[0][n] = __builtin_amdgcn_mfma_f32_16x16x32_bf16(fa0, fg, accg[0][n], 0, 0, 0);
      accg[1][n] = __builtin_amdgcn_mfma_f32_16x16x32_bf16(fa1, fg, accg[1][n], 0, 0, 0);
      accu[0][n] = __builtin_amdgcn_mfma_f32_16x16x32_bf16(fa0, fu, accu[0][n], 0, 0, 0);
      accu[1][n] = __builtin_amdgcn_mfma_f32_16x16x32_bf16(fa1, fu, accu[1][n], 0, 0, 0);
    }
    __syncthreads();
  }
  #pragma unroll
  for (int r = 0; r < 2; ++r) {
    #pragma unroll
    for (int i = 0; i < 4; ++i) {
      const int m = m0 + 32 * w + 16 * r + qq * 4 + i;
      if (m < cnt) {
        unsigned short* orow = hff + (size_t)(off + m) * FF + n0;
        #pragma unroll
        for (int n = 0; n < 4; ++n) {
          const float g = accg[r][n][i], u = accu[r][n][i];
          orow[n * 16 + l15] = f2bf(g / (1.f + __expf(-g)) * u);
        }
      }
    }
  }
}

// ---------------- MoE MFMA grouped GEMM 2: pout = (h_ff @ Wd) * pair_w ----------------
__global__ __launch_bounds__(256) void moe_gemm2_mfma(const unsigned short* __restrict__ hff,
                                                      const float* __restrict__ Wd,
                                                      const float* __restrict__ pair_w,
                                                      const int* __restrict__ offs,
                                                      float* __restrict__ pout) {
  const int e = blockIdx.z;
  const int off = offs[e], cnt = offs[e + 1] - off;
  const int m0 = blockIdx.y * 128;
  if (m0 >= cnt) return;
  const int n0 = blockIdx.x * 64;
  const float* Bsrc = Wd + (size_t)e * FF * HID;
  __shared__ unsigned short As[128][40];
  __shared__ unsigned short Bs[64][40];
  const int tid = threadIdx.x;
  const int lane = tid & 63, w = tid >> 6;
  const int l15 = lane & 15, qq = lane >> 4;
  const int ar = tid >> 1, ah = tid & 1;
  const int bk = tid >> 3, bc8 = tid & 7;
  const int bshift = 8 * (bc8 & 1);
  int srow = off + m0 + ar;
  if (srow > 2 * S - 1) srow = 2 * S - 1;
  const unsigned short* xrow = hff + (size_t)srow * FF;
  const int aoff = qq * 8 + 8 * (l15 & 1);
  const int boff = qq * 8 + 8 * ((l15 >> 3) & 1);
  f32x4 acc[2][4];
  #pragma unroll
  for (int r = 0; r < 2; ++r)
    #pragma unroll
    for (int n = 0; n < 4; ++n) acc[r][n] = (f32x4){0.f, 0.f, 0.f, 0.f};
  for (int k0 = 0; k0 < FF; k0 += 32) {
    const u16x8 a0 = *(const u16x8*)(xrow + k0 + ah * 16);
    const u16x8 a1 = *(const u16x8*)(xrow + k0 + ah * 16 + 8);
    const int aw = ah * 16 + 8 * (ar & 1);
    *(u16x8*)&As[ar][aw] = a0;
    *(u16x8*)&As[ar][aw + 8] = a1;
    const float* brow = Bsrc + (size_t)(k0 + bk) * HID + n0 + bc8 * 8;
    const float4 b0 = *(const float4*)(brow);
    const float4 b1 = *(const float4*)(brow + 4);
    const float bv[8] = {b0.x, b0.y, b0.z, b0.w, b1.x, b1.y, b1.z, b1.w};
    #pragma unroll
    for (int ii = 0; ii < 8; ++ii) Bs[bc8 * 8 + ii][bk + bshift] = f2bf(bv[ii]);
    __syncthreads();
    const bf16x8 fa0 = *(const bf16x8*)&As[32 * w + l15][aoff];
    const bf16x8 fa1 = *(const bf16x8*)&As[32 * w + 16 + l15][aoff];
    #pragma unroll
    for (int n = 0; n < 4; ++n) {
      const bf16x8 fb = *(const bf16x8*)&Bs[n * 16 + l15][boff];
      acc[0][n] = __builtin_amdgcn_mfma_f32_16x16x32_bf16(fa0, fb, acc[0][n], 0, 0, 0);
      acc[1][n] = __builtin_amdgcn_mfma_f32_16x16x32_bf16(fa1, fb, acc[1][n], 0, 0, 0);
    }
    __syncthreads();
  }
  #pragma unroll
  for (int r = 0; r < 2; ++r) {
    #pragma unroll
    for (int i = 0; i < 4; ++i) {
      const int m = m0 + 32 * w + 16 * r + qq * 4 + i;
      if (m < cnt) {
        const float pw = pair_w[off + m];
        float* orow = pout + (size_t)(off + m) * HID + n0;
        #pragma unroll
        for (int n = 0; n < 4; ++n) orow[n * 16 + l15] = acc[r][n][i] * pw;
      }
    }
  }
}

// ---------------- final: out = h + pair_out[pos0] + pair_out[pos1] ----------------
__global__ __launch_bounds__(256) void final_kernel(const float* __restrict__ h,
                                                    const float* __restrict__ pout,
                                                    const int* __restrict__ pos_of,
                                                    float* __restrict__ out) {
  const int gid = blockIdx.x * 256 + threadIdx.x;  // S*HID
  const int t = gid / HID, c = gid - t * HID;
  const int p0 = pos_of[2 * t], p1 = pos_of[2 * t + 1];
  out[gid] = h[gid] + pout[(size_t)p0 * HID + c] + pout[(size_t)p1 * HID + c];
}

// ---------------- launch ----------------
extern "C" void kernel_launch(void* const* d_in, const int* in_sizes, int n_in,
                              void* d_out, int out_size, void* d_ws, size_t ws_size,
                              hipStream_t stream) {
  const float* x         = (const float*)d_in[0];
  const float* norm1_w   = (const float*)d_in[1];
  const float* w_qkv     = (const float*)d_in[2];
  const float* w_out     = (const float*)d_in[3];
  const float* norm2_w   = (const float*)d_in[4];
  const float* w_router  = (const float*)d_in[5];
  const float* w_gate_up = (const float*)d_in[6];
  const float* w_down    = (const float*)d_in[7];
  float* out = (float*)d_out;

  char* p = (char*)d_ws;
  auto alloc = [&](size_t bytes) -> void* {
    void* r = (void*)p;
    p += (bytes + 255) & ~(size_t)255;
    return r;
  };
  float* xn       = (float*)alloc((size_t)S * HID * 4);
  float* qkv      = (float*)alloc((size_t)S * DQKV * 4);
  float* cosb     = (float*)alloc((size_t)S * 32 * 4);
  float* sinb     = (float*)alloc((size_t)S * 32 * 4);
  float* q_rope   = (float*)alloc((size_t)S * NQ * HD * 4);
  float* k_rope   = (float*)alloc((size_t)S * NKV * HD * 4);
  float* ctxb     = (float*)alloc((size_t)S * HID * 4);
  float* hbuf     = (float*)alloc((size_t)S * HID * 4);
  float* moe_in   = (float*)alloc((size_t)S * HID * 4);
  unsigned short* mo_bf = (unsigned short*)alloc((size_t)S * HID * 2);
  unsigned short* h_ff  = (unsigned short*)alloc((size_t)2 * S * FF * 2);
  float* pout     = (float*)alloc((size_t)2 * S * HID * 4);
  float* wnorm    = (float*)alloc((size_t)S * 2 * 4);
  float* pair_w   = (float*)alloc((size_t)S * 2 * 4);
  int* eidx       = (int*)alloc((size_t)S * 2 * 4);
  int* counts     = (int*)alloc(64 * 4);
  int* offs       = (int*)alloc(64 * 4);
  int* cursors    = (int*)alloc(64 * 4);
  int* pair_token = (int*)alloc((size_t)S * 2 * 4);
  int* pos_of     = (int*)alloc((size_t)S * 2 * 4);

  rmsnorm_kernel<<<S, 256, 0, stream>>>(x, norm1_w, xn);
  rope_tab_kernel<<<(S * 32) / 256, 256, 0, stream>>>(cosb, sinb);
  gemm_rn_kernel<<<dim3(DQKV / 64, S / 64), 256, 0, stream>>>(xn, w_qkv, qkv, nullptr, S, DQKV, HID);
  rope_apply_kernel<<<(S * 15 * 32) / 256, 256, 0, stream>>>(qkv, cosb, sinb, q_rope, k_rope);
  attn_v2_kernel<<<dim3(S / 64, NQ), 256, 0, stream>>>(q_rope, k_rope, qkv, ctxb);
  gemm_rn_kernel<<<dim3(HID / 64, S / 64), 256, 0, stream>>>(ctxb, w_out, hbuf, x, S, HID, HID);
  rmsnorm_kernel<<<S, 256, 0, stream>>>(hbuf, norm2_w, moe_in);
  cast_bf_kernel<<<(S * HID / 4) / 256, 256, 0, stream>>>(moe_in, mo_bf);
  zero_counts_kernel<<<1, 64, 0, stream>>>(counts);
  router_kernel<<<S, 256, 0, stream>>>(moe_in, w_router, eidx, wnorm, counts);
  offsets_kernel<<<1, 1, 0, stream>>>(counts, offs, cursors);
  scatter_kernel<<<S / 256, 256, 0, stream>>>(eidx, wnorm, cursors, pair_token, pair_w, pos_of);
  moe_gemm1_mfma<<<dim3(FF / 64, 16, NE), 256, 0, stream>>>(mo_bf, w_gate_up, pair_token, offs, h_ff);
  moe_gemm2_mfma<<<dim3(HID / 64, 16, NE), 256, 0, stream>>>(h_ff, w_down, pair_w, offs, pout);
  final_kernel<<<(S * HID) / 256, 256, 0, stream>>>(hbuf, pout, pos_of, out);
}